// Round 4
// baseline (11704.626 us; speedup 1.0000x reference)
//
#include <hip/hip_runtime.h>

#define B_ 64
#define T_ 2048
#define F_ 8
#define H_ 128

typedef _Float16 v2h __attribute__((ext_vector_type(2)));

// pack two fp32 into one dword of two f16 (RTN via cast)
__device__ __forceinline__ unsigned pk2h(float lo, float hi) {
    v2h p;
    p[0] = (_Float16)lo;
    p[1] = (_Float16)hi;
    return __builtin_bit_cast(unsigned, p);
}

#if __has_builtin(__builtin_amdgcn_fdot2)
__device__ __forceinline__ float fdot2a(unsigned a, unsigned b, float c) {
    return __builtin_amdgcn_fdot2(__builtin_bit_cast(v2h, a),
                                  __builtin_bit_cast(v2h, b), c, false);
}
#else
__device__ __forceinline__ float fdot2a(unsigned a, unsigned b, float c) {
    v2h av = __builtin_bit_cast(v2h, a);
    v2h bv = __builtin_bit_cast(v2h, b);
    c += (float)av[0] * (float)bv[0];
    c += (float)av[1] * (float)bv[1];
    return c;
}
#endif

__device__ __forceinline__ float sigm(float x) {
    return 1.0f / (1.0f + __expf(-x));
}
__device__ __forceinline__ float tanh_f(float x) {
    float e = __expf(2.0f * x);
    return 1.0f - 2.0f / (e + 1.0f);
}

// In-quad / in-octet lane exchanges (DPP for ^1,^2; ds_swizzle for ^4)
#if __has_builtin(__builtin_amdgcn_mov_dpp)
template <int CTRL>
__device__ __forceinline__ float qperm(float v) {
    int i = __builtin_bit_cast(int, v);
    i = __builtin_amdgcn_mov_dpp(i, CTRL, 0xF, 0xF, true);
    return __builtin_bit_cast(float, i);
}
__device__ __forceinline__ float lane_xor1(float v) { return qperm<0xB1>(v); } // [1,0,3,2]
__device__ __forceinline__ float lane_xor2(float v) { return qperm<0x4E>(v); } // [2,3,0,1]
#else
__device__ __forceinline__ float lane_xor1(float v) {
    int i = __builtin_amdgcn_ds_swizzle(__builtin_bit_cast(int, v), 0x041F);
    return __builtin_bit_cast(float, i);
}
__device__ __forceinline__ float lane_xor2(float v) {
    int i = __builtin_amdgcn_ds_swizzle(__builtin_bit_cast(int, v), 0x081F);
    return __builtin_bit_cast(float, i);
}
#endif
__device__ __forceinline__ float lane_xor4(float v) {
    int i = __builtin_amdgcn_ds_swizzle(__builtin_bit_cast(int, v), 0x101F);
    return __builtin_bit_cast(float, i);
}

// ===================== Phase 1: layer 0 only =====================
// 512 threads: tid = h_idx*4 + sub; sub -> gate order [i,g,f,o] via grow.
// Per-thread full row: 68 weight dwords (fits arch VGPRs). 1 barrier/tick.
// Streams h0(t) (64 packed-f16 dwords) to global workspace.
__global__ __launch_bounds__(512, 1)
void lstm_l0_kernel(const float* __restrict__ x,
                    const float* __restrict__ wih0,
                    const float* __restrict__ whh0,
                    const float* __restrict__ bih0,
                    const float* __restrict__ bhh0,
                    unsigned* __restrict__ h0g)
{
    __shared__ __align__(16) unsigned x_lds[T_ * F_ / 2];   // 32 KB packed f16 x
    __shared__ __align__(16) unsigned h0_p[2][H_ / 2];      // double-buffered h0

    const int tid   = threadIdx.x;
    const int b     = blockIdx.x;
    const int h_idx = tid >> 2;
    const int sub   = tid & 3;
    const int grow  = (0x3120 >> (sub * 4)) & 0xF;          // {0,2,1,3}[sub]
    const int row   = grow * H_ + h_idx;

    // stage x[b] into LDS as packed f16 pairs
    const float4* xp = (const float4*)(x + (size_t)b * T_ * F_);
    #pragma unroll
    for (int i = 0; i < 8; ++i) {
        int idx = tid + i * 512;
        float4 v = xp[idx];
        x_lds[idx * 2 + 0] = pk2h(v.x, v.y);
        x_lds[idx * 2 + 1] = pk2h(v.z, v.w);
    }

    unsigned rwih0[4];
    {
        const float4* p = (const float4*)(wih0 + (size_t)row * F_);
        float4 v0 = p[0], v1 = p[1];
        rwih0[0] = pk2h(v0.x, v0.y); rwih0[1] = pk2h(v0.z, v0.w);
        rwih0[2] = pk2h(v1.x, v1.y); rwih0[3] = pk2h(v1.z, v1.w);
    }
    unsigned rwhh0[64];
    {
        const float4* p = (const float4*)(whh0 + (size_t)row * H_);
        #pragma unroll
        for (int i = 0; i < 32; ++i) {
            float4 v = p[i];
            rwhh0[i * 2 + 0] = pk2h(v.x, v.y);
            rwhh0[i * 2 + 1] = pk2h(v.z, v.w);
        }
    }
    const float bias0 = bih0[row] + bhh0[row];

    if (tid < H_ / 2) { h0_p[0][tid] = 0u; h0_p[1][tid] = 0u; }
    __syncthreads();

    const bool is_g = (sub == 1);
    const bool lo2  = (sub < 2);
    float c0 = 0.0f;
    unsigned* dst = h0g + (size_t)b * T_ * (H_ / 2);

    for (int t = 0; t < T_; ++t) {
        const int rp = (t + 1) & 1;   // holds h0(t-1)
        const int wp = t & 1;         // receives h0(t)

        float aa = bias0, ab = 0.0f;
        uint4 xv = *(const uint4*)&x_lds[t * 4];
        aa = fdot2a(rwih0[0], xv.x, aa);
        ab = fdot2a(rwih0[1], xv.y, ab);
        aa = fdot2a(rwih0[2], xv.z, aa);
        ab = fdot2a(rwih0[3], xv.w, ab);
        const unsigned* hr = &h0_p[rp][0];
        #pragma unroll 4
        for (int j = 0; j < 16; ++j) {
            uint4 hv = *(const uint4*)&hr[j * 4];
            aa = fdot2a(rwhh0[j * 4 + 0], hv.x, aa);
            ab = fdot2a(rwhh0[j * 4 + 1], hv.y, ab);
            aa = fdot2a(rwhh0[j * 4 + 2], hv.z, aa);
            ab = fdot2a(rwhh0[j * 4 + 3], hv.w, ab);
        }
        float a = aa + ab;
        float xin = is_g ? 2.0f * a : a;
        float s   = sigm(xin);
        float act = is_g ? 2.0f * s - 1.0f : s;   // tanh via sigmoid, branch-free
        float s1  = lane_xor1(act);
        float p   = lo2 ? act * s1 : (sub == 2 ? act : s1) * c0;
        float cn  = p + lane_xor2(p);
        c0 = cn;
        float oval = (sub == 2) ? s1 : act;
        float h = oval * tanh_f(cn);
        if (sub == 2) ((_Float16*)&h0_p[wp][0])[h_idx] = (_Float16)h;

        __syncthreads();   // h0(t) visible

        // stream h0(t) out (stable until t+2; two barriers separate reuse)
        if (tid < H_ / 2) dst[(size_t)t * (H_ / 2) + tid] = h0_p[wp][tid];
    }
}

// ===================== Phase 2: layer 1 + output =====================
// 1024 threads: tid = h_idx*8 + gslot*2 + half; half-row dots (64 weight
// dwords -> register-clean at 4 waves/SIMD). h0 stream prefetched with a
// register-pended distance-2 pipeline into a 4-slot LDS ring.
__global__ __launch_bounds__(1024, 1)
void lstm_l1_kernel(const unsigned* __restrict__ h0g,
                    const float* __restrict__ wih1,
                    const float* __restrict__ whh1,
                    const float* __restrict__ bih1,
                    const float* __restrict__ bhh1,
                    const float* __restrict__ wlin,
                    const float* __restrict__ blin,
                    float* __restrict__ out)
{
    __shared__ __align__(16) unsigned h0_ring[4][H_ / 2];   // h0 ring (packed f16)
    __shared__ __align__(16) unsigned h1_p[2][H_ / 2];      // double-buffered h1
    __shared__ __align__(16) unsigned wlin_p[512];
    __shared__ float blin_f[F_];

    const int tid   = threadIdx.x;
    const int b     = blockIdx.x;
    const int h_idx = tid >> 3;
    const int sub   = tid & 7;
    const int gslot = sub >> 1;
    const int half  = sub & 1;
    const int grow  = (0x3120 >> (gslot * 4)) & 0xF;        // {0,2,1,3}[gslot]
    const int row   = grow * H_ + h_idx;

    unsigned rwih1[32], rwhh1[32];
    {
        const float4* p = (const float4*)(wih1 + (size_t)row * H_ + half * 64);
        #pragma unroll
        for (int i = 0; i < 16; ++i) {
            float4 v = p[i];
            rwih1[i * 2 + 0] = pk2h(v.x, v.y);
            rwih1[i * 2 + 1] = pk2h(v.z, v.w);
        }
    }
    {
        const float4* p = (const float4*)(whh1 + (size_t)row * H_ + half * 64);
        #pragma unroll
        for (int i = 0; i < 16; ++i) {
            float4 v = p[i];
            rwhh1[i * 2 + 0] = pk2h(v.x, v.y);
            rwhh1[i * 2 + 1] = pk2h(v.z, v.w);
        }
    }
    const float bias1 = bih1[row] + bhh1[row];

    if (tid < 512) {
        float2 v = ((const float2*)wlin)[tid];
        wlin_p[tid] = pk2h(v.x, v.y);
    }
    if (tid < F_) blin_f[tid] = blin[tid];
    if (tid < H_ / 2) { h1_p[0][tid] = 0u; h1_p[1][tid] = 0u; }

    const unsigned* src = h0g + (size_t)b * T_ * (H_ / 2);

    // prime ring slots 0,1 with h0(0), h0(1); pend register holds h0(2)
    if (tid < 128) {
        int tt = tid >> 6, lane = tid & 63;
        h0_ring[tt][lane] = src[(size_t)tt * 64 + lane];
    }
    unsigned pend = 0;
    if (tid >= 64 && tid < 128) pend = src[(size_t)2 * 64 + (tid - 64)];
    __syncthreads();

    const bool is_g = (gslot == 1);
    const bool lo4  = (sub < 4);
    const bool lt6  = (sub < 6);
    float c1 = 0.0f;

    for (int t = 0; t <= T_; ++t) {
        const int rp = (t + 1) & 1;   // holds h1(t-1)
        const int wp = t & 1;         // receives h1(t)

        if (t < T_) {
            const unsigned* h0r = &h0_ring[t & 3][half * 32];   // h0(t)
            const unsigned* h1r = &h1_p[rp][half * 32];         // h1(t-1)
            float aa = 0.0f, ab = 0.0f, ba = 0.0f, bb = 0.0f;
            #pragma unroll 4
            for (int j = 0; j < 8; ++j) {
                uint4 hv0 = *(const uint4*)&h0r[j * 4];
                uint4 hv1 = *(const uint4*)&h1r[j * 4];
                aa = fdot2a(rwih1[j * 4 + 0], hv0.x, aa);
                ab = fdot2a(rwih1[j * 4 + 1], hv0.y, ab);
                aa = fdot2a(rwih1[j * 4 + 2], hv0.z, aa);
                ab = fdot2a(rwih1[j * 4 + 3], hv0.w, ab);
                ba = fdot2a(rwhh1[j * 4 + 0], hv1.x, ba);
                bb = fdot2a(rwhh1[j * 4 + 1], hv1.y, bb);
                ba = fdot2a(rwhh1[j * 4 + 2], hv1.z, ba);
                bb = fdot2a(rwhh1[j * 4 + 3], hv1.w, bb);
            }
            float a = (aa + ab) + (ba + bb);
            a += lane_xor1(a);             // combine half-row sums (lane^1)
            a += bias1;
            float xin = is_g ? 2.0f * a : a;
            float s   = sigm(xin);
            float act = is_g ? 2.0f * s - 1.0f : s;
            float s1  = lane_xor2(act);    // gate partner (gslot^1)
            float p   = lo4 ? act * s1 : (lt6 ? act : s1) * c1;
            float cn  = p + lane_xor4(p);  // i*g + f*c (gslot^2)
            c1 = cn;
            float oval = lt6 ? s1 : act;
            float h = oval * tanh_f(cn);
            if (sub == 4) ((_Float16*)&h1_p[wp][0])[h_idx] = (_Float16)h;  // h1(t)
        }

        // wave-1 lanes: write pended h0(t+2) into ring, issue load of h0(t+3)
        if (tid >= 64 && tid < 128) {
            int lane = tid - 64;
            if (t + 2 < T_) h0_ring[(t + 2) & 3][lane] = pend;
            if (t + 3 < T_) pend = src[(size_t)(t + 3) * 64 + lane];
        }

        // OUT(t-1) from h1(t-1) (parity rp), wave 0
        if (t >= 1 && tid < 64) {
            int fo = tid >> 3;
            int l  = tid & 7;
            const unsigned* hp = &h1_p[rp][0];
            float a = 0.0f;
            #pragma unroll
            for (int jj = 0; jj < 8; ++jj) {
                a = fdot2a(wlin_p[fo * 64 + l * 8 + jj], hp[l * 8 + jj], a);
            }
            a += __shfl_down(a, 4, 8);
            a += __shfl_down(a, 2, 8);
            a += __shfl_down(a, 1, 8);
            if (l == 0) {
                out[((size_t)b * T_ + (t - 1)) * F_ + fo] = a + blin_f[fo];
            }
        }

        __syncthreads();
    }
}

// ===================== Fallback (round-3 verified kernel) =====================
__global__ __launch_bounds__(512, 2)
void lstm2_2bar_kernel(const float* __restrict__ x,
                       const float* __restrict__ wih0,
                       const float* __restrict__ whh0,
                       const float* __restrict__ bih0,
                       const float* __restrict__ bhh0,
                       const float* __restrict__ wih1,
                       const float* __restrict__ whh1,
                       const float* __restrict__ bih1,
                       const float* __restrict__ bhh1,
                       const float* __restrict__ wlin,
                       const float* __restrict__ blin,
                       float* __restrict__ out)
{
    __shared__ __align__(16) unsigned x_lds[T_ * F_ / 2];
    __shared__ __align__(16) unsigned h0_p[2][H_ / 2];
    __shared__ __align__(16) unsigned h1_p[2][H_ / 2];
    __shared__ __align__(16) unsigned wlin_p[512];
    __shared__ float blin_f[F_];

    const int tid   = threadIdx.x;
    const int b     = blockIdx.x;
    const int h_idx = tid >> 2;
    const int sub   = tid & 3;
    const int grow  = (0x3120 >> (sub * 4)) & 0xF;
    const int row   = grow * H_ + h_idx;

    const float4* xp = (const float4*)(x + (size_t)b * T_ * F_);
    #pragma unroll
    for (int i = 0; i < 8; ++i) {
        int idx = tid + i * 512;
        float4 v = xp[idx];
        x_lds[idx * 2 + 0] = pk2h(v.x, v.y);
        x_lds[idx * 2 + 1] = pk2h(v.z, v.w);
    }

    unsigned rwih0[4];
    {
        const float4* p = (const float4*)(wih0 + (size_t)row * F_);
        float4 v0 = p[0], v1 = p[1];
        rwih0[0] = pk2h(v0.x, v0.y); rwih0[1] = pk2h(v0.z, v0.w);
        rwih0[2] = pk2h(v1.x, v1.y); rwih0[3] = pk2h(v1.z, v1.w);
    }
    unsigned rwhh0[64], rwih1[64], rwhh1[64];
    {
        const float4* p = (const float4*)(whh0 + (size_t)row * H_);
        #pragma unroll
        for (int i = 0; i < 32; ++i) {
            float4 v = p[i];
            rwhh0[i * 2 + 0] = pk2h(v.x, v.y);
            rwhh0[i * 2 + 1] = pk2h(v.z, v.w);
        }
    }
    {
        const float4* p = (const float4*)(wih1 + (size_t)row * H_);
        #pragma unroll
        for (int i = 0; i < 32; ++i) {
            float4 v = p[i];
            rwih1[i * 2 + 0] = pk2h(v.x, v.y);
            rwih1[i * 2 + 1] = pk2h(v.z, v.w);
        }
    }
    {
        const float4* p = (const float4*)(whh1 + (size_t)row * H_);
        #pragma unroll
        for (int i = 0; i < 32; ++i) {
            float4 v = p[i];
            rwhh1[i * 2 + 0] = pk2h(v.x, v.y);
            rwhh1[i * 2 + 1] = pk2h(v.z, v.w);
        }
    }
    const float bias0 = bih0[row] + bhh0[row];
    const float bias1 = bih1[row] + bhh1[row];

    {
        float2 v = ((const float2*)wlin)[tid];
        wlin_p[tid] = pk2h(v.x, v.y);
    }
    if (tid < F_) blin_f[tid] = blin[tid];
    if (tid < H_ / 2) {
        h0_p[0][tid] = 0u; h0_p[1][tid] = 0u;
        h1_p[0][tid] = 0u; h1_p[1][tid] = 0u;
    }
    __syncthreads();

    const bool is_g = (sub == 1);
    const bool lo2  = (sub < 2);
    float c0 = 0.0f, c1 = 0.0f;

    for (int t = 0; t <= T_; ++t) {
        const int rp = (t + 1) & 1;
        const int wp = t & 1;

        if (t < T_) {
            float aa = bias0, ab = 0.0f;
            uint4 xv = *(const uint4*)&x_lds[t * 4];
            aa = fdot2a(rwih0[0], xv.x, aa);
            ab = fdot2a(rwih0[1], xv.y, ab);
            aa = fdot2a(rwih0[2], xv.z, aa);
            ab = fdot2a(rwih0[3], xv.w, ab);
            const unsigned* hr = &h0_p[rp][0];
            #pragma unroll
            for (int j = 0; j < 16; ++j) {
                uint4 hv = *(const uint4*)&hr[j * 4];
                aa = fdot2a(rwhh0[j * 4 + 0], hv.x, aa);
                ab = fdot2a(rwhh0[j * 4 + 1], hv.y, ab);
                aa = fdot2a(rwhh0[j * 4 + 2], hv.z, aa);
                ab = fdot2a(rwhh0[j * 4 + 3], hv.w, ab);
            }
            float a = aa + ab;
            float xin = is_g ? 2.0f * a : a;
            float s   = sigm(xin);
            float act = is_g ? 2.0f * s - 1.0f : s;
            float s1  = lane_xor1(act);
            float p   = lo2 ? act * s1 : (sub == 2 ? act : s1) * c0;
            float cn  = p + lane_xor2(p);
            c0 = cn;
            float oval = (sub == 2) ? s1 : act;
            float h = oval * tanh_f(cn);
            if (sub == 2) ((_Float16*)&h0_p[wp][0])[h_idx] = (_Float16)h;
        }

        if (t >= 1 && tid < 64) {
            int fo = tid >> 3;
            int l  = tid & 7;
            const unsigned* hp = &h1_p[rp][0];
            float a = 0.0f;
            #pragma unroll
            for (int jj = 0; jj < 8; ++jj) {
                a = fdot2a(wlin_p[fo * 64 + l * 8 + jj], hp[l * 8 + jj], a);
            }
            a += __shfl_down(a, 4, 8);
            a += __shfl_down(a, 2, 8);
            a += __shfl_down(a, 1, 8);
            if (l == 0) {
                out[((size_t)b * T_ + (t - 1)) * F_ + fo] = a + blin_f[fo];
            }
        }

        __syncthreads();

        if (t < T_) {
            float aa = bias1, ab = 0.0f, ba = 0.0f, bb = 0.0f;
            const unsigned* h0r = &h0_p[wp][0];
            const unsigned* h1r = &h1_p[rp][0];
            #pragma unroll
            for (int j = 0; j < 16; ++j) {
                uint4 hv0 = *(const uint4*)&h0r[j * 4];
                uint4 hv1 = *(const uint4*)&h1r[j * 4];
                aa = fdot2a(rwih1[j * 4 + 0], hv0.x, aa);
                ab = fdot2a(rwih1[j * 4 + 1], hv0.y, ab);
                aa = fdot2a(rwih1[j * 4 + 2], hv0.z, aa);
                ab = fdot2a(rwih1[j * 4 + 3], hv0.w, ab);
                ba = fdot2a(rwhh1[j * 4 + 0], hv1.x, ba);
                bb = fdot2a(rwhh1[j * 4 + 1], hv1.y, bb);
                ba = fdot2a(rwhh1[j * 4 + 2], hv1.z, ba);
                bb = fdot2a(rwhh1[j * 4 + 3], hv1.w, bb);
            }
            float a = (aa + ab) + (ba + bb);
            float xin = is_g ? 2.0f * a : a;
            float s   = sigm(xin);
            float act = is_g ? 2.0f * s - 1.0f : s;
            float s1  = lane_xor1(act);
            float p   = lo2 ? act * s1 : (sub == 2 ? act : s1) * c1;
            float cn  = p + lane_xor2(p);
            c1 = cn;
            float oval = (sub == 2) ? s1 : act;
            float h = oval * tanh_f(cn);
            if (sub == 2) ((_Float16*)&h1_p[wp][0])[h_idx] = (_Float16)h;
        }

        __syncthreads();
    }
}

extern "C" void kernel_launch(void* const* d_in, const int* in_sizes, int n_in,
                              void* d_out, int out_size, void* d_ws, size_t ws_size,
                              hipStream_t stream) {
    const float* x    = (const float*)d_in[0];
    const float* wih0 = (const float*)d_in[1];
    const float* whh0 = (const float*)d_in[2];
    const float* bih0 = (const float*)d_in[3];
    const float* bhh0 = (const float*)d_in[4];
    const float* wih1 = (const float*)d_in[5];
    const float* whh1 = (const float*)d_in[6];
    const float* bih1 = (const float*)d_in[7];
    const float* bhh1 = (const float*)d_in[8];
    const float* wlin = (const float*)d_in[9];
    const float* blin = (const float*)d_in[10];
    float* out = (float*)d_out;

    const size_t need = (size_t)B_ * T_ * (H_ / 2) * sizeof(unsigned);  // 33.5 MB
    if (ws_size >= need && d_ws != nullptr) {
        unsigned* h0g = (unsigned*)d_ws;
        lstm_l0_kernel<<<dim3(B_), dim3(512), 0, stream>>>(
            x, wih0, whh0, bih0, bhh0, h0g);
        lstm_l1_kernel<<<dim3(B_), dim3(1024), 0, stream>>>(
            h0g, wih1, whh1, bih1, bhh1, wlin, blin, out);
    } else {
        lstm2_2bar_kernel<<<dim3(B_), dim3(512), 0, stream>>>(
            x, wih0, whh0, bih0, bhh0, wih1, whh1, bih1, bhh1, wlin, blin, out);
    }
}

// Round 5
// 3162.204 us; speedup vs baseline: 3.7014x; 3.7014x over previous
//
#include <hip/hip_runtime.h>

#define B_ 64
#define T_ 2048
#define F_ 8
#define H_ 128

typedef _Float16 v2h __attribute__((ext_vector_type(2)));

// pack two fp32 into one dword of two f16 (RTN via cast)
__device__ __forceinline__ unsigned pk2h(float lo, float hi) {
    v2h p;
    p[0] = (_Float16)lo;
    p[1] = (_Float16)hi;
    return __builtin_bit_cast(unsigned, p);
}

#if __has_builtin(__builtin_amdgcn_fdot2)
__device__ __forceinline__ float fdot2a(unsigned a, unsigned b, float c) {
    return __builtin_amdgcn_fdot2(__builtin_bit_cast(v2h, a),
                                  __builtin_bit_cast(v2h, b), c, false);
}
#else
__device__ __forceinline__ float fdot2a(unsigned a, unsigned b, float c) {
    v2h av = __builtin_bit_cast(v2h, a);
    v2h bv = __builtin_bit_cast(v2h, b);
    c += (float)av[0] * (float)bv[0];
    c += (float)av[1] * (float)bv[1];
    return c;
}
#endif

__device__ __forceinline__ float sigm(float x) {
    return 1.0f / (1.0f + __expf(-x));
}
__device__ __forceinline__ float tanh_f(float x) {
    float e = __expf(2.0f * x);
    return 1.0f - 2.0f / (e + 1.0f);
}

// In-quad lane exchanges via DPP quad_perm (VALU pipe, no LDS)
#if __has_builtin(__builtin_amdgcn_mov_dpp)
template <int CTRL>
__device__ __forceinline__ float qperm(float v) {
    int i = __builtin_bit_cast(int, v);
    i = __builtin_amdgcn_mov_dpp(i, CTRL, 0xF, 0xF, true);
    return __builtin_bit_cast(float, i);
}
__device__ __forceinline__ float lane_xor1(float v) { return qperm<0xB1>(v); } // [1,0,3,2]
__device__ __forceinline__ float lane_xor2(float v) { return qperm<0x4E>(v); } // [2,3,0,1]
#else
__device__ __forceinline__ float lane_xor1(float v) {
    int i = __builtin_amdgcn_ds_swizzle(__builtin_bit_cast(int, v), 0x041F);
    return __builtin_bit_cast(float, i);
}
__device__ __forceinline__ float lane_xor2(float v) {
    int i = __builtin_amdgcn_ds_swizzle(__builtin_bit_cast(int, v), 0x081F);
    return __builtin_bit_cast(float, i);
}
#endif

#define RING_LD 68   // 64 dwords + 4 pad: breaks same-bank stride in the OUT burst

// Thread map (512 threads): tid = h_idx*4 + sub
//   h_idx 0..127; sub 0..3 -> gate order [i, g, f, o] (rows {0,2,1,3}*128 + h_idx).
// Cell update fully in-quad (verified bit-identical vs gates[]-LDS version):
//   act lanes: 0:sig(i) 1:tanh(g) 2:sig(f) 3:sig(o)
//   s1 = xor1(act): 0:tanh(g) 1:sig(i) 2:sig(o) 3:sig(f)
//   p  = sub<2 ? act*s1 : (sub==2 ? act : s1)*c    -> lanes01: i*g, lanes23: f*c
//   c' = p + xor2(p)  == i*g + f*c (replicated in quad)
//   h  = sig(o) * tanh(c'); lane sub==2 (oval=s1) writes h (f16) to LDS.
//
// Tick structure (2 barriers/tick; barriers double as register-pressure fences —
// round-2 showed a single merged region spills):
//   Phase A: L0 dots(t) + quad update + h0(t) write
//   barrier
//   Phase B: L1 dots(t) + quad update + h1(t) -> 64-slot LDS ring
//   barrier
//   every 64 ticks: OUT burst — 512 threads compute 64 ticks x 8 features,
//   one coalesced store. Global stores (and their pre-barrier vmcnt drains)
//   happen 32x per sequence instead of 2048x (round-4 lesson: __syncthreads
//   drains vmcnt(0), so any per-tick global op serializes its latency).
__global__ __launch_bounds__(512, 2)
void lstm2_burst_kernel(const float* __restrict__ x,
                        const float* __restrict__ wih0,
                        const float* __restrict__ whh0,
                        const float* __restrict__ bih0,
                        const float* __restrict__ bhh0,
                        const float* __restrict__ wih1,
                        const float* __restrict__ whh1,
                        const float* __restrict__ bih1,
                        const float* __restrict__ bhh1,
                        const float* __restrict__ wlin,
                        const float* __restrict__ blin,
                        float* __restrict__ out)
{
    __shared__ __align__(16) unsigned x_lds[T_ * F_ / 2];     // 32 KB packed f16 x
    __shared__ __align__(16) unsigned h0_p[2][H_ / 2];        // double-buffered h0
    __shared__ __align__(16) unsigned h1_ring[64 * RING_LD];  // 64-tick h1 ring (17 KB)
    __shared__ __align__(16) unsigned wlin_p[F_ * RING_LD];   // w_lin rows, padded
    __shared__ float blin_f[F_];

    const int tid   = threadIdx.x;
    const int b     = blockIdx.x;
    const int h_idx = tid >> 2;
    const int sub   = tid & 3;                          // quad lane == gate slot
    const int grow  = (0x3120 >> (sub * 4)) & 0xF;      // {0,2,1,3}[sub]
    const int row   = grow * H_ + h_idx;                // gate row (PyTorch i,f,g,o layout)

    // ---- stage x[b] into LDS as packed f16 pairs ----
    const float4* xp = (const float4*)(x + (size_t)b * T_ * F_);
    #pragma unroll
    for (int i = 0; i < 8; ++i) {
        int idx = tid + i * 512;          // 4096 float4 total
        float4 v = xp[idx];
        x_lds[idx * 2 + 0] = pk2h(v.x, v.y);
        x_lds[idx * 2 + 1] = pk2h(v.z, v.w);
    }

    // ---- per-thread full-row weights -> VGPRs/AGPRs (196 packed dwords) ----
    unsigned rwih0[4];
    {
        const float4* p = (const float4*)(wih0 + (size_t)row * F_);
        float4 v0 = p[0], v1 = p[1];
        rwih0[0] = pk2h(v0.x, v0.y); rwih0[1] = pk2h(v0.z, v0.w);
        rwih0[2] = pk2h(v1.x, v1.y); rwih0[3] = pk2h(v1.z, v1.w);
    }
    unsigned rwhh0[64], rwih1[64], rwhh1[64];
    {
        const float4* p = (const float4*)(whh0 + (size_t)row * H_);
        #pragma unroll
        for (int i = 0; i < 32; ++i) {
            float4 v = p[i];
            rwhh0[i * 2 + 0] = pk2h(v.x, v.y);
            rwhh0[i * 2 + 1] = pk2h(v.z, v.w);
        }
    }
    {
        const float4* p = (const float4*)(wih1 + (size_t)row * H_);
        #pragma unroll
        for (int i = 0; i < 32; ++i) {
            float4 v = p[i];
            rwih1[i * 2 + 0] = pk2h(v.x, v.y);
            rwih1[i * 2 + 1] = pk2h(v.z, v.w);
        }
    }
    {
        const float4* p = (const float4*)(whh1 + (size_t)row * H_);
        #pragma unroll
        for (int i = 0; i < 32; ++i) {
            float4 v = p[i];
            rwhh1[i * 2 + 0] = pk2h(v.x, v.y);
            rwhh1[i * 2 + 1] = pk2h(v.z, v.w);
        }
    }
    const float bias0 = bih0[row] + bhh0[row];
    const float bias1 = bih1[row] + bhh1[row];

    // w_lin: [8][128] fp32 -> padded rows of 64 packed pairs
    {
        int r = tid >> 6, c = tid & 63;                 // r 0..7, c 0..63
        float2 v = ((const float2*)wlin)[r * 64 + c];
        wlin_p[r * RING_LD + c] = pk2h(v.x, v.y);
    }
    if (tid < F_) blin_f[tid] = blin[tid];
    if (tid < H_ / 2) { h0_p[0][tid] = 0u; h0_p[1][tid] = 0u; }
    // zero ring slot 63 (read as h1(-1) at t=0)
    if (tid < H_ / 2) h1_ring[63 * RING_LD + tid] = 0u;
    __syncthreads();

    const bool is_g = (sub == 1);
    const bool lo2  = (sub < 2);
    float c0 = 0.0f, c1 = 0.0f;    // cell state, replicated across each quad

    for (int t = 0; t < T_; ++t) {
        const int rp = (t + 1) & 1;   // parity holding h0(t-1)
        const int wp = t & 1;         // parity receiving h0(t)

        // ---------- phase A: layer 0 at t ----------
        {
            float aa = bias0, ab = 0.0f;
            uint4 xv = *(const uint4*)&x_lds[t * 4];
            aa = fdot2a(rwih0[0], xv.x, aa);
            ab = fdot2a(rwih0[1], xv.y, ab);
            aa = fdot2a(rwih0[2], xv.z, aa);
            ab = fdot2a(rwih0[3], xv.w, ab);
            const unsigned* hr = &h0_p[rp][0];            // h0(t-1)
            #pragma unroll
            for (int j = 0; j < 16; ++j) {
                uint4 hv = *(const uint4*)&hr[j * 4];
                aa = fdot2a(rwhh0[j * 4 + 0], hv.x, aa);
                ab = fdot2a(rwhh0[j * 4 + 1], hv.y, ab);
                aa = fdot2a(rwhh0[j * 4 + 2], hv.z, aa);
                ab = fdot2a(rwhh0[j * 4 + 3], hv.w, ab);
            }
            float a = aa + ab;
            float xin = is_g ? 2.0f * a : a;
            float s   = sigm(xin);
            float act = is_g ? 2.0f * s - 1.0f : s;       // tanh via sigmoid, branch-free
            float s1  = lane_xor1(act);
            float p   = lo2 ? act * s1 : (sub == 2 ? act : s1) * c0;
            float cn  = p + lane_xor2(p);
            c0 = cn;
            float oval = (sub == 2) ? s1 : act;
            float h = oval * tanh_f(cn);
            if (sub == 2) ((_Float16*)&h0_p[wp][0])[h_idx] = (_Float16)h;  // h0(t)
        }

        __syncthreads();   // h0(t) visible; scheduling/pressure fence

        // ---------- phase B: layer 1 at t ----------
        {
            float aa = bias1, ab = 0.0f, ba = 0.0f, bb = 0.0f;
            const unsigned* h0r = &h0_p[wp][0];                         // h0(t)
            const unsigned* h1r = &h1_ring[((t + 63) & 63) * RING_LD];  // h1(t-1)
            #pragma unroll
            for (int j = 0; j < 16; ++j) {
                uint4 hv0 = *(const uint4*)&h0r[j * 4];
                uint4 hv1 = *(const uint4*)&h1r[j * 4];
                aa = fdot2a(rwih1[j * 4 + 0], hv0.x, aa);
                ab = fdot2a(rwih1[j * 4 + 1], hv0.y, ab);
                aa = fdot2a(rwih1[j * 4 + 2], hv0.z, aa);
                ab = fdot2a(rwih1[j * 4 + 3], hv0.w, ab);
                ba = fdot2a(rwhh1[j * 4 + 0], hv1.x, ba);
                bb = fdot2a(rwhh1[j * 4 + 1], hv1.y, bb);
                ba = fdot2a(rwhh1[j * 4 + 2], hv1.z, ba);
                bb = fdot2a(rwhh1[j * 4 + 3], hv1.w, bb);
            }
            float a = (aa + ab) + (ba + bb);
            float xin = is_g ? 2.0f * a : a;
            float s   = sigm(xin);
            float act = is_g ? 2.0f * s - 1.0f : s;
            float s1  = lane_xor1(act);
            float p   = lo2 ? act * s1 : (sub == 2 ? act : s1) * c1;
            float cn  = p + lane_xor2(p);
            c1 = cn;
            float oval = (sub == 2) ? s1 : act;
            float h = oval * tanh_f(cn);
            if (sub == 2)
                ((_Float16*)&h1_ring[(t & 63) * RING_LD])[h_idx] = (_Float16)h; // h1(t)
        }

        __syncthreads();   // h1(t) visible; pressure fence

        // ---------- OUT burst: every 64 ticks, 512 outputs in parallel ----------
        if ((t & 63) == 63) {
            const int tick_i = tid >> 3;   // 0..63 -> tick (t-63+tick_i); ring slot == tick_i
            const int fo     = tid & 7;    // output feature
            const unsigned* hp = &h1_ring[tick_i * RING_LD];
            const unsigned* wv = &wlin_p[fo * RING_LD];
            float a = 0.0f;
            #pragma unroll
            for (int j = 0; j < 16; ++j) {
                uint4 hv = *(const uint4*)&hp[j * 4];
                uint4 wq = *(const uint4*)&wv[j * 4];
                a = fdot2a(wq.x, hv.x, a);
                a = fdot2a(wq.y, hv.y, a);
                a = fdot2a(wq.z, hv.z, a);
                a = fdot2a(wq.w, hv.w, a);
            }
            // tid-consecutive -> address-consecutive: fully coalesced 2 KB store
            out[(size_t)b * T_ * F_ + (size_t)(t - 63) * F_ + tid] = a + blin_f[fo];
            // store drains at the NEXT phase-A barrier (once per 64 ticks, all waves)
        }
    }
}

extern "C" void kernel_launch(void* const* d_in, const int* in_sizes, int n_in,
                              void* d_out, int out_size, void* d_ws, size_t ws_size,
                              hipStream_t stream) {
    const float* x    = (const float*)d_in[0];
    const float* wih0 = (const float*)d_in[1];
    const float* whh0 = (const float*)d_in[2];
    const float* bih0 = (const float*)d_in[3];
    const float* bhh0 = (const float*)d_in[4];
    const float* wih1 = (const float*)d_in[5];
    const float* whh1 = (const float*)d_in[6];
    const float* bih1 = (const float*)d_in[7];
    const float* bhh1 = (const float*)d_in[8];
    const float* wlin = (const float*)d_in[9];
    const float* blin = (const float*)d_in[10];
    float* out = (float*)d_out;

    lstm2_burst_kernel<<<dim3(B_), dim3(512), 0, stream>>>(
        x, wih0, whh0, bih0, bhh0, wih1, whh1, bih1, bhh1, wlin, blin, out);
}